// Round 7
// baseline (59.814 us; speedup 1.0000x reference)
//
#include <hip/hip_runtime.h>
#include <hip/hip_bf16.h>

#define TOKS 2048
#define FEAT 2048
#define NR   128
#define KB   32

typedef __attribute__((ext_vector_type(8))) short bf16x8;
typedef __attribute__((ext_vector_type(4))) float f32x4;

__device__ __forceinline__ unsigned short f2bf(float f) {
    unsigned u = __builtin_bit_cast(unsigned, f);
    u += 0x7FFFu + ((u >> 16) & 1u);
    return (unsigned short)(u >> 16);
}

__device__ __forceinline__ bf16x8 pack8(float4 a, float4 b) {
    bf16x8 r;
    r[0] = (short)f2bf(a.x); r[1] = (short)f2bf(a.y);
    r[2] = (short)f2bf(a.z); r[3] = (short)f2bf(a.w);
    r[4] = (short)f2bf(b.x); r[5] = (short)f2bf(b.y);
    r[6] = (short)f2bf(b.z); r[7] = (short)f2bf(b.w);
    return r;
}

// Values-stationary block-sparse MFMA kernel (single dispatch).
//   grid = 8 r-blocks x 32 token-spans = 256 blocks, 512 threads (8 waves).
//   Each wave owns 2 r's: loads B-fragments ONCE, then streams 4 token-tiles
//   (16 tokens each) through double-buffered LDS. Steady state has no global
//   frag reloads on the critical path.
__global__ __launch_bounds__(512) void bsp7(const float* __restrict__ x,
                                            const float* __restrict__ values,
                                            const int* __restrict__ cols,
                                            const float* __restrict__ bias,
                                            float* __restrict__ out) {
    __shared__ __align__(16) unsigned short xs[2 * 16 * FEAT];   // 2 x 64 KiB

    int bid  = blockIdx.x;
    int rblk = bid >> 5;                 // 0..7   (bid%8 spreads spans across XCDs)
    int span = bid & 31;                 // 0..31
    int tok0 = span * 64;
    int r0   = rblk * 16;
    int tid  = threadIdx.x;
    int wave = tid >> 6;
    int lane = tid & 63;
    int n = lane & 15;          // token-in-subtile == output i == D col
    int g = lane >> 4;          // k-quarter
    int h = g & 1;              // 8-elem half within a 16-wide block
    int q = g >> 1;             // which gathered block of the MFMA pair
    int mrow = n << 12;         // LDS row base (bytes)
    int axor = (n & 7) << 4;    // swizzle term

    int tr = tid >> 8;          // 0..1
    int ch = tid & 255;         // 16B chunk within a 4 KiB bf16 row

    // ---- issue tile-0 staging loads (16 rows) ----
    float4 sa[8], sb[8];
    {
        const float* base = x + (size_t)tok0 * FEAT + ch * 8;
        #pragma unroll
        for (int it = 0; it < 8; ++it) {
            const float4* p = reinterpret_cast<const float4*>(base + (size_t)(it * 2 + tr) * FEAT);
            sa[it] = p[0]; sb[it] = p[1];
        }
    }

    // ---- load B-fragments for both r's ONCE (fp32 -> bf16 pack) ----
    int rA = r0 + wave * 2, rB = rA + 1;
    bf16x8 bfA[16], bfB[16];
    int aaA[16], aaB[16];
    {
        int cb = __builtin_amdgcn_readfirstlane(rA) * KB;
        const float* vfl = values + ((size_t)rA << 13) + (q << 8) + (n << 4) + (h << 3);
        #pragma unroll
        for (int t = 0; t < 16; ++t) {
            const float4* pv = reinterpret_cast<const float4*>(vfl + t * 512);
            bfA[t] = pack8(pv[0], pv[1]);
            int c0 = cols[cb + 2 * t];
            int c1 = cols[cb + 2 * t + 1];
            int c  = q ? c1 : c0;
            aaA[t] = mrow + (((c << 5) + (h << 4)) ^ axor);
        }
    }
    {
        int cb = __builtin_amdgcn_readfirstlane(rB) * KB;
        const float* vfl = values + ((size_t)rB << 13) + (q << 8) + (n << 4) + (h << 3);
        #pragma unroll
        for (int t = 0; t < 16; ++t) {
            const float4* pv = reinterpret_cast<const float4*>(vfl + t * 512);
            bfB[t] = pack8(pv[0], pv[1]);
            int c0 = cols[cb + 2 * t];
            int c1 = cols[cb + 2 * t + 1];
            int c  = q ? c1 : c0;
            aaB[t] = mrow + (((c << 5) + (h << 4)) ^ axor);
        }
    }
    float fbA = bias[(rA << 4) + n];
    float fbB = bias[(rB << 4) + n];

    // ---- write tile-0 to buf0 (swizzled) ----
    #pragma unroll
    for (int it = 0; it < 8; ++it) {
        int t = it * 2 + tr;
        int off = (t << 12) + ((ch << 4) ^ ((t & 7) << 4));
        *reinterpret_cast<bf16x8*>(reinterpret_cast<char*>(xs) + off) = pack8(sa[it], sb[it]);
    }
    __syncthreads();

    #pragma unroll 1
    for (int tile = 0; tile < 4; ++tile) {
        const char* xb = reinterpret_cast<const char*>(xs) + ((tile & 1) << 16);
        char*       xw = reinterpret_cast<char*>(xs) + (((tile + 1) & 1) << 16);
        const float* nbase = x + (size_t)(tok0 + (tile + 1) * 16) * FEAT + ch * 8;
        bool pf = (tile < 3);

        // issue half-1 of next tile (rows 0..7)
        if (pf) {
            #pragma unroll
            for (int it = 0; it < 4; ++it) {
                const float4* p = reinterpret_cast<const float4*>(nbase + (size_t)(it * 2 + tr) * FEAT);
                sa[it] = p[0]; sb[it] = p[1];
            }
        }

        // compute rA on current buffer (two independent chains)
        f32x4 a0 = {0.f, 0.f, 0.f, 0.f}, a1 = {0.f, 0.f, 0.f, 0.f};
        #pragma unroll
        for (int t = 0; t < 8; ++t) {
            bf16x8 x0 = *reinterpret_cast<const bf16x8*>(xb + aaA[2 * t]);
            bf16x8 x1 = *reinterpret_cast<const bf16x8*>(xb + aaA[2 * t + 1]);
            a0 = __builtin_amdgcn_mfma_f32_16x16x32_bf16(x0, bfA[2 * t],     a0, 0, 0, 0);
            a1 = __builtin_amdgcn_mfma_f32_16x16x32_bf16(x1, bfA[2 * t + 1], a1, 0, 0, 0);
        }

        // write half-1, issue half-2 (rows 8..15)
        if (pf) {
            #pragma unroll
            for (int it = 0; it < 4; ++it) {
                int t = it * 2 + tr;
                int off = (t << 12) + ((ch << 4) ^ ((t & 7) << 4));
                *reinterpret_cast<bf16x8*>(xw + off) = pack8(sa[it], sb[it]);
            }
            #pragma unroll
            for (int it = 4; it < 8; ++it) {
                const float4* p = reinterpret_cast<const float4*>(nbase + (size_t)(it * 2 + tr) * FEAT);
                sa[it] = p[0]; sb[it] = p[1];
            }
        }

        // compute rB
        f32x4 b0 = {0.f, 0.f, 0.f, 0.f}, b1 = {0.f, 0.f, 0.f, 0.f};
        #pragma unroll
        for (int t = 0; t < 8; ++t) {
            bf16x8 x0 = *reinterpret_cast<const bf16x8*>(xb + aaB[2 * t]);
            bf16x8 x1 = *reinterpret_cast<const bf16x8*>(xb + aaB[2 * t + 1]);
            b0 = __builtin_amdgcn_mfma_f32_16x16x32_bf16(x0, bfB[2 * t],     b0, 0, 0, 0);
            b1 = __builtin_amdgcn_mfma_f32_16x16x32_bf16(x1, bfB[2 * t + 1], b1, 0, 0, 0);
        }

        // write half-2
        if (pf) {
            #pragma unroll
            for (int it = 4; it < 8; ++it) {
                int t = it * 2 + tr;
                int off = (t << 12) + ((ch << 4) ^ ((t & 7) << 4));
                *reinterpret_cast<bf16x8*>(xw + off) = pack8(sa[it], sb[it]);
            }
        }

        // store outputs for this 16-token tile
        int trow = tok0 + tile * 16 + (g << 2);
        size_t obA = (size_t)trow * 2048 + (rA << 4) + n;
        size_t obB = (size_t)trow * 2048 + (rB << 4) + n;
        #pragma unroll
        for (int p = 0; p < 4; ++p) {
            out[obA + (size_t)p * 2048] = a0[p] + a1[p] + fbA;
            out[obB + (size_t)p * 2048] = b0[p] + b1[p] + fbB;
        }

        __syncthreads();
    }
}

extern "C" void kernel_launch(void* const* d_in, const int* in_sizes, int n_in,
                              void* d_out, int out_size, void* d_ws, size_t ws_size,
                              hipStream_t stream) {
    const float* x      = (const float*)d_in[0];
    const float* values = (const float*)d_in[1];
    const int*   cols   = (const int*)d_in[2];
    const float* bias   = (const float*)d_in[3];
    float*       out    = (float*)d_out;

    bsp7<<<256, 512, 0, stream>>>(x, values, cols, bias, out);
}

// Round 8
// 27.348 us; speedup vs baseline: 2.1872x; 2.1872x over previous
//
#include <hip/hip_runtime.h>
#include <hip/hip_bf16.h>

#define TOKS 2048
#define FEAT 2048
#define NR   128
#define KB   32
#define RB   32
#define TT   32

typedef __attribute__((ext_vector_type(8))) short bf16x8;
typedef __attribute__((ext_vector_type(4))) float f32x4;

__device__ __forceinline__ unsigned short f2bf(float f) {
    unsigned u = __builtin_bit_cast(unsigned, f);
    u += 0x7FFFu + ((u >> 16) & 1u);
    return (unsigned short)(u >> 16);
}

__device__ __forceinline__ bf16x8 pack8(float4 a, float4 b) {
    bf16x8 r;
    r[0] = (short)f2bf(a.x); r[1] = (short)f2bf(a.y);
    r[2] = (short)f2bf(a.z); r[3] = (short)f2bf(a.w);
    r[4] = (short)f2bf(b.x); r[5] = (short)f2bf(b.y);
    r[6] = (short)f2bf(b.z); r[7] = (short)f2bf(b.w);
    return r;
}

// Cheap fp32->bf16 pair pack: round-half-up (+0x8000) then v_perm hi16s.
// 3 VALU per 2 elements (vs ~6 for full RTNE f2bf). Max rel err 2^-9.
__device__ __forceinline__ unsigned pack2_hu(float lo, float hi) {
    unsigned a = __builtin_bit_cast(unsigned, lo) + 0x8000u;
    unsigned b = __builtin_bit_cast(unsigned, hi) + 0x8000u;
    return __builtin_amdgcn_perm(b, a, 0x07060302u);  // [hi16(b) : hi16(a)]
}

__device__ __forceinline__ bf16x8 pack8_hu(float4 a, float4 b) {
    unsigned r0 = pack2_hu(a.x, a.y);
    unsigned r1 = pack2_hu(a.z, a.w);
    unsigned r2 = pack2_hu(b.x, b.y);
    unsigned r3 = pack2_hu(b.z, b.w);
    uint4 u = {r0, r1, r2, r3};
    return __builtin_bit_cast(bf16x8, u);
}

// Single-dispatch block-sparse MFMA kernel.
//   grid = 256 blocks (1/CU), 512 threads (8 waves). r1's exact L2 geometry:
//   per XCD: 8 token-groups (2 MB x) + all 4 r-groups (values fp32 4 MB,
//   ~L2/L3 mixed, amortized 64x per byte).
__global__ __launch_bounds__(512) void bsp8(const float* __restrict__ x,
                                            const float* __restrict__ values,
                                            const int* __restrict__ cols,
                                            const float* __restrict__ bias,
                                            float* __restrict__ out) {
    __shared__ __align__(16) unsigned short xs[TT * FEAT];   // 128 KiB

    int bid  = blockIdx.x;
    int xcd  = bid & 7, slot = bid >> 3;          // slot 0..31
    int tg   = xcd * 8 + (slot >> 2);             // token group 0..63 (8 per XCD)
    int rg   = slot & 3;                          // r group 0..3
    int tok0 = tg * TT;
    int r0   = rg * RB;
    int tid  = threadIdx.x;

    // ---- stage x tile: fp32 -> bf16 (RTNE), [32][2048] with byte-XOR swizzle ----
    {
        int tr = tid >> 8;          // 0..1 : token parity
        int ch = tid & 255;         // 16B chunk within row (8 bf16)
        #pragma unroll 4
        for (int it = 0; it < TT / 2; ++it) {
            int t = it * 2 + tr;
            const float4* p = reinterpret_cast<const float4*>(
                x + (size_t)(tok0 + t) * FEAT + ch * 8);
            float4 a = p[0], b = p[1];
            int off = (t << 12) + ((ch << 4) ^ ((t & 7) << 4));
            *reinterpret_cast<bf16x8*>(reinterpret_cast<char*>(xs) + off) = pack8(a, b);
        }
    }
    __syncthreads();

    int wave = tid >> 6;
    int lane = tid & 63;
    int n = lane & 15;          // token-in-subtile == output i == D col
    int g = lane >> 4;          // k-quarter
    int h = g & 1;              // 8-elem half within a 16-wide block
    int q = g >> 1;             // which gathered block of the MFMA pair

    int mrow = n << 12;              // LDS row base (bytes)
    int axor = (n & 7) << 4;         // swizzle term

    #pragma unroll 1
    for (int rr = 0; rr < 4; ++rr) {
        int r = r0 + wave * 4 + rr;
        int cbase = __builtin_amdgcn_readfirstlane(r) * KB;

        bf16x8 bfrag[16];
        int aaddr[16];
        const float* vfl = values + ((size_t)r << 13) + (q << 8) + (n << 4) + (h << 3);
        // chunks of 4 frags: 8 dwordx4 in flight (32 VGPR transient), then pack
        #pragma unroll
        for (int tc = 0; tc < 4; ++tc) {
            #pragma unroll
            for (int ti = 0; ti < 4; ++ti) {
                int t = tc * 4 + ti;
                const float4* pv = reinterpret_cast<const float4*>(vfl + t * 512);
                bfrag[t] = pack8_hu(pv[0], pv[1]);
                int c0 = cols[cbase + 2 * t];       // wave-uniform -> s_load
                int c1 = cols[cbase + 2 * t + 1];
                int c  = q ? c1 : c0;
                aaddr[t] = mrow + (((c << 5) + (h << 4)) ^ axor);
            }
        }

        float fb = bias[(r << 4) + n];

        #pragma unroll
        for (int sx = 0; sx < 2; ++sx) {
            const char* xb = reinterpret_cast<const char*>(xs) + (sx << 16);
            f32x4 acc0 = {0.f, 0.f, 0.f, 0.f};
            f32x4 acc1 = {0.f, 0.f, 0.f, 0.f};
            __builtin_amdgcn_s_setprio(1);
            #pragma unroll
            for (int t = 0; t < 8; ++t) {
                bf16x8 a0 = *reinterpret_cast<const bf16x8*>(xb + aaddr[2 * t]);
                bf16x8 a1 = *reinterpret_cast<const bf16x8*>(xb + aaddr[2 * t + 1]);
                acc0 = __builtin_amdgcn_mfma_f32_16x16x32_bf16(a0, bfrag[2 * t],     acc0, 0, 0, 0);
                acc1 = __builtin_amdgcn_mfma_f32_16x16x32_bf16(a1, bfrag[2 * t + 1], acc1, 0, 0, 0);
            }
            __builtin_amdgcn_s_setprio(0);
            int trow = tok0 + (sx << 4) + (g << 2);
            size_t ob = (size_t)trow * 2048 + (r << 4) + n;
            #pragma unroll
            for (int p = 0; p < 4; ++p)
                out[ob + (size_t)p * 2048] = acc0[p] + acc1[p] + fb;
        }
    }
}

extern "C" void kernel_launch(void* const* d_in, const int* in_sizes, int n_in,
                              void* d_out, int out_size, void* d_ws, size_t ws_size,
                              hipStream_t stream) {
    const float* x      = (const float*)d_in[0];
    const float* values = (const float*)d_in[1];
    const int*   cols   = (const int*)d_in[2];
    const float* bias   = (const float*)d_in[3];
    float*       out    = (float*)d_out;

    const int grid = (TOKS / TT) * (NR / RB);      // 256
    bsp8<<<grid, 512, 0, stream>>>(x, values, cols, bias, out);
}